// Round 3
// baseline (38.667 us; speedup 1.0000x reference)
//
#include <hip/hip_runtime.h>

// BilateralSliceApply, pipelined: grid [4,12,8,16,16] f32, guide [4,1024,1024],
// image [4,3,1024,1024] -> out [4,3,1024,1024].
//
// 1024 blocks x 256 threads; each block owns 4 consecutive image rows.
// Double-buffered y-lerped grid slab in LDS (s[2][16][100]); per iteration:
//   issue next row's pixel+grid loads -> compute current row -> write next
//   slab -> barrier.  HBM streaming overlaps the LDS/VALU compute phase.

static constexpr int C_ = 12, D_ = 8, GH_ = 16, GW_ = 16;
static constexpr int H_ = 1024, W_ = 1024;
static constexpr int HW_ = H_ * W_;
static constexpr int XS = D_ * C_ + 4;   // 100 floats = 400 B (16B multiple)
static constexpr int R_ = 4;             // rows per block

__global__ __launch_bounds__(256, 4) void bsa_pipe_kernel(
    const float* __restrict__ grid,   // [B][C][D][GH][GW]
    const float* __restrict__ guide,  // [B][H][W]
    const float* __restrict__ image,  // [B][3][H][W]
    float* __restrict__ out)          // [B][3][H][W]
{
    __shared__ float s[2][GW_ * XS];  // 2 x 6.4 KB

    const int t = threadIdx.x;
    const int xp = t << 2;                       // 4 pixels/thread
    const int row0 = blockIdx.x * R_;            // global row = b*H + y
    const int b = row0 >> 10;                    // 1024 % R_ == 0: no b-crossing
    const float* gb  = grid  + b * (C_ * D_ * GH_ * GW_);
    const float* gdb = guide + (size_t)b * HW_;
    const float* imb = image + (size_t)b * 3 * HW_;
    float*       ofb = out   + (size_t)b * 3 * HW_;

    // ---- staging role: threads 0..191; elem (e=0..7): x=t&15, z=e, c=t>>4
    // global reads stay 64B-coalesced per 16 lanes; LDS write banks
    // 4x + 12z + c cover all 32 banks at 2-way (free).
    const bool stager = (t < 192);
    const int sx = t & 15, sc = t >> 4;
    const int sg_base = sc * (D_ * GH_ * GW_) + sx;   // + z*256 + y*16
    const int sl_base = sx * XS + sc;                 // + z*12

    // ---- per-thread x-cell (constant across rows; 4-aligned pixel groups
    // never straddle an x-cell boundary: boundaries at x = 64k+31.5)
    const float gxc = (xp + 0.5f) * (1.0f / 64.0f) - 0.5f;
    const float fx = floorf(gxc);
    const int ix = (int)fx;
    const int x0 = min(max(ix, 0), GW_ - 1);
    const int x1 = min(max(ix + 1, 0), GW_ - 1);
    const float txb = gxc - fx;

    float4 pg[2], pr[2], pgr[2], pb[2];   // double-buffered pixel inputs
    float sv0[8], sv1[8];                 // slab staging regs (single set)

    auto issue_pix = [&](int row, int p) {
        const size_t ro = (size_t)(row & (H_ - 1)) * W_ + xp;
        pg[p]  = *(const float4*)(gdb + ro);
        pr[p]  = *(const float4*)(imb + ro);
        pgr[p] = *(const float4*)(imb + HW_ + ro);
        pb[p]  = *(const float4*)(imb + 2 * (size_t)HW_ + ro);
    };

    auto issue_slab = [&](int row) {
        if (!stager) return;
        const int y = row & (H_ - 1);
        const float gyc = (y + 0.5f) * (1.0f / 64.0f) - 0.5f;
        const int iy = (int)floorf(gyc);
        const int y0 = min(max(iy, 0), GH_ - 1) << 4;
        const int y1 = min(max(iy + 1, 0), GH_ - 1) << 4;
#pragma unroll
        for (int e = 0; e < 8; ++e) {
            sv0[e] = gb[sg_base + e * 256 + y0];
            sv1[e] = gb[sg_base + e * 256 + y1];
        }
    };

    auto write_slab = [&](int row, int bf) {
        if (stager) {
            const int y = row & (H_ - 1);
            const float gyc = (y + 0.5f) * (1.0f / 64.0f) - 0.5f;
            const float ty = gyc - floorf(gyc);
#pragma unroll
            for (int e = 0; e < 8; ++e)
                s[bf][sl_base + e * C_] = sv0[e] + ty * (sv1[e] - sv0[e]);
        }
        __syncthreads();
    };

    auto compute_row = [&](int row, int p, int bf) {
        const float* sb = s[bf];
        const float* s0 = sb + x0 * XS;
        const float* s1 = sb + x1 * XS;
        const float gzv[4] = {pg[p].x, pg[p].y, pg[p].z, pg[p].w};
        const float rv[4]  = {pr[p].x, pr[p].y, pr[p].z, pr[p].w};
        const float gv[4]  = {pgr[p].x, pgr[p].y, pgr[p].z, pgr[p].w};
        const float bv[4]  = {pb[p].x, pb[p].y, pb[p].z, pb[p].w};
        float o0[4], o1[4], o2[4];

#pragma unroll
        for (int j = 0; j < 4; ++j) {
            const float tx = txb + j * (1.0f / 64.0f);
            const float gz = gzv[j] * (float)D_ - 0.5f;
            const float fz = floorf(gz);
            const float tz = gz - fz;
            const int iz = (int)fz;
            const int z0 = min(max(iz, 0), D_ - 1);
            const int z1 = min(max(iz + 1, 0), D_ - 1);

            const float w00 = (1.f - tx) * (1.f - tz);
            const float w01 = (1.f - tx) * tz;
            const float w10 = tx * (1.f - tz);
            const float w11 = tx * tz;

            const float* p00 = s0 + z0 * C_;
            const float* p01 = s0 + z1 * C_;
            const float* p10 = s1 + z0 * C_;
            const float* p11 = s1 + z1 * C_;

#pragma unroll
            for (int k = 0; k < 3; ++k) {
                float4 a0 = *(const float4*)(p00 + 4 * k);
                float4 a1 = *(const float4*)(p01 + 4 * k);
                float4 a2 = *(const float4*)(p10 + 4 * k);
                float4 a3 = *(const float4*)(p11 + 4 * k);
                float cx = w00 * a0.x + w01 * a1.x + w10 * a2.x + w11 * a3.x;
                float cy = w00 * a0.y + w01 * a1.y + w10 * a2.y + w11 * a3.y;
                float cz = w00 * a0.z + w01 * a1.z + w10 * a2.z + w11 * a3.z;
                float cw = w00 * a0.w + w01 * a1.w + w10 * a2.w + w11 * a3.w;
                float res = cx * rv[j] + cy * gv[j] + cz * bv[j] + cw;
                if (k == 0) o0[j] = res;
                else if (k == 1) o1[j] = res;
                else o2[j] = res;
            }
        }

        float* ob = ofb + (size_t)(row & (H_ - 1)) * W_ + xp;
        *(float4*)(ob)                    = make_float4(o0[0], o0[1], o0[2], o0[3]);
        *(float4*)(ob + HW_)              = make_float4(o1[0], o1[1], o1[2], o1[3]);
        *(float4*)(ob + 2 * (size_t)HW_)  = make_float4(o2[0], o2[1], o2[2], o2[3]);
    };

    // ---- prologue: stage row 0 ----
    issue_slab(row0);
    issue_pix(row0, 0);
    write_slab(row0, 0);      // waits slab loads, fills buf0, barrier

    // ---- pipelined main loop ----
#pragma unroll
    for (int r = 0; r < R_; ++r) {
        const int p = r & 1, bf = r & 1;
        if (r + 1 < R_) {
            issue_pix(row0 + r + 1, p ^ 1);   // HBM loads in flight...
            issue_slab(row0 + r + 1);
        }
        compute_row(row0 + r, p, bf);         // ...hidden under LDS/VALU
        if (r + 1 < R_) write_slab(row0 + r + 1, bf ^ 1);  // wait + write + barrier
    }
}

extern "C" void kernel_launch(void* const* d_in, const int* in_sizes, int n_in,
                              void* d_out, int out_size, void* d_ws, size_t ws_size,
                              hipStream_t stream) {
    const float* grid  = (const float*)d_in[0];
    const float* guide = (const float*)d_in[1];
    const float* image = (const float*)d_in[2];
    float* out = (float*)d_out;

    bsa_pipe_kernel<<<(4 * H_) / R_, 256, 0, stream>>>(grid, guide, image, out);
}

// Round 4
// 24.441 us; speedup vs baseline: 1.5820x; 1.5820x over previous
//
#include <hip/hip_runtime.h>

// BilateralSliceApply: grid [4,12,8,16,16] f32, guide [4,1024,1024] f32,
// image [4,3,1024,1024] f32 -> out [4,3,1024,1024] f32.
//
// One block per image row. The row's y-lerped grid slab (16 x-cells * 8 z * 12
// coeffs) is staged in LDS. Pixel->lane mapping p = j*256 + t: each wave-instr
// covers 64 CONSECUTIVE pixels = only 2 distinct x-cells, so every
// ds_read_b128 quad sees <=2 distinct addresses (same-z lanes broadcast) ->
// bank-conflict-free. I/O is scalar b32 but fully coalesced (256B/instr).

static constexpr int C_ = 12, D_ = 8, GH_ = 16, GW_ = 16;
static constexpr int H_ = 1024, W_ = 1024;
static constexpr int HW_ = H_ * W_;
static constexpr int XS = D_ * C_ + 4;   // 100 floats; 16B-aligned x-slabs

__global__ __launch_bounds__(256) void bsa_row_kernel(
    const float* __restrict__ grid,   // [B][C][D][GH][GW]
    const float* __restrict__ guide,  // [B][H][W]
    const float* __restrict__ image,  // [B][3][H][W]
    float* __restrict__ out)          // [B][3][H][W]
{
    __shared__ float s[GW_ * XS];     // 6.4 KB

    const int bid = blockIdx.x;       // = b*H + y
    const int y = bid & (H_ - 1);
    const int b = bid >> 10;
    const int t = threadIdx.x;

    // ---- y interpolation factors (uniform across block) ----
    const float gyc = (y + 0.5f) * (1.0f / 64.0f) - 0.5f;
    const float fy = floorf(gyc);
    const float ty = gyc - fy;
    const int iy = (int)fy;
    const int y0 = min(max(iy, 0), GH_ - 1);
    const int y1 = min(max(iy + 1, 0), GH_ - 1);

    // ---- issue slab global loads FIRST (threads 0..191) ----
    // mapping: x = t&15, c = t>>4, z = unrolled 0..7.
    // LDS write bank = (4x + c + 12z) mod 32 -> 2-way over 64 lanes (free).
    const int sx = t & 15, sc = t >> 4;
    float sv0[8], sv1[8];
    const float* gb = grid + b * (C_ * D_ * GH_ * GW_);
    if (t < 192) {
        const int base = sc * (D_ * GH_ * GW_) + sx;
#pragma unroll
        for (int z = 0; z < 8; ++z) {
            sv0[z] = gb[base + z * (GH_ * GW_) + y0 * GW_];
            sv1[z] = gb[base + z * (GH_ * GW_) + y1 * GW_];
        }
    }

    // ---- issue all pixel loads (stay in flight under slab write) ----
    const float* gdp = guide + (size_t)bid * W_;
    const float* imp = image + (size_t)b * 3 * HW_ + (size_t)y * W_;
    float gz4[4], r4[4], g4[4], b4[4];
#pragma unroll
    for (int j = 0; j < 4; ++j) {
        const int p = j * 256 + t;
        gz4[j] = gdp[p];
        r4[j]  = imp[p];
        g4[j]  = imp[HW_ + p];
        b4[j]  = imp[2 * HW_ + p];
    }

    // ---- y-lerp slab into LDS ----
    if (t < 192) {
#pragma unroll
        for (int z = 0; z < 8; ++z)
            s[sx * XS + z * C_ + sc] = sv0[z] + ty * (sv1[z] - sv0[z]);
    }
    __syncthreads();

    // ---- compute: 4 strided pixels per thread ----
    float* const ob = out + (size_t)b * 3 * HW_ + (size_t)y * W_;
#pragma unroll
    for (int j = 0; j < 4; ++j) {
        const int p = j * 256 + t;

        const float gxc = (p + 0.5f) * (1.0f / 64.0f) - 0.5f;
        const float fx = floorf(gxc);
        const float tx = gxc - fx;
        const int ix = (int)fx;
        const int x0 = min(max(ix, 0), GW_ - 1);
        const int x1 = min(max(ix + 1, 0), GW_ - 1);

        const float gz = gz4[j] * (float)D_ - 0.5f;
        const float fz = floorf(gz);
        const float tz = gz - fz;
        const int iz = (int)fz;
        const int z0 = min(max(iz, 0), D_ - 1);
        const int z1 = min(max(iz + 1, 0), D_ - 1);

        const float w00 = (1.f - tx) * (1.f - tz);
        const float w01 = (1.f - tx) * tz;
        const float w10 = tx * (1.f - tz);
        const float w11 = tx * tz;

        const float* p00 = s + x0 * XS + z0 * C_;
        const float* p01 = s + x0 * XS + z1 * C_;
        const float* p10 = s + x1 * XS + z0 * C_;
        const float* p11 = s + x1 * XS + z1 * C_;

        const float rv = r4[j], gv = g4[j], bv = b4[j];

#pragma unroll
        for (int k = 0; k < 3; ++k) {
            float4 a0 = *(const float4*)(p00 + 4 * k);
            float4 a1 = *(const float4*)(p01 + 4 * k);
            float4 a2 = *(const float4*)(p10 + 4 * k);
            float4 a3 = *(const float4*)(p11 + 4 * k);
            float cx = w00 * a0.x + w01 * a1.x + w10 * a2.x + w11 * a3.x;
            float cy = w00 * a0.y + w01 * a1.y + w10 * a2.y + w11 * a3.y;
            float cz = w00 * a0.z + w01 * a1.z + w10 * a2.z + w11 * a3.z;
            float cw = w00 * a0.w + w01 * a1.w + w10 * a2.w + w11 * a3.w;
            ob[k * HW_ + p] = cx * rv + cy * gv + cz * bv + cw;
        }
    }
}

extern "C" void kernel_launch(void* const* d_in, const int* in_sizes, int n_in,
                              void* d_out, int out_size, void* d_ws, size_t ws_size,
                              hipStream_t stream) {
    const float* grid  = (const float*)d_in[0];
    const float* guide = (const float*)d_in[1];
    const float* image = (const float*)d_in[2];
    float* out = (float*)d_out;

    bsa_row_kernel<<<4 * H_, 256, 0, stream>>>(grid, guide, image, out);
}